// Round 9
// baseline (113.781 us; speedup 1.0000x reference)
//
#include <hip/hip_runtime.h>
#include <math.h>

#define N_NODES 50000
#define DEG 16
#define E_EDGES (N_NODES * DEG)
#define FIN 128
#define FTOT 192   // 2*FQK + FV
#define FQK 64
#define FV 64
#define H 8

typedef __attribute__((ext_vector_type(8))) short short8;
typedef __attribute__((ext_vector_type(4))) float float4v;

__device__ inline unsigned short f2bf(float f) {
    unsigned int u = __float_as_uint(f);
    unsigned int r = u + 0x7fffu + ((u >> 16) & 1u);  // RNE
    return (unsigned short)(r >> 16);
}
__device__ inline float bflo(unsigned int w) { return __uint_as_float(w << 16); }
__device__ inline float bfhi(unsigned int w) { return __uint_as_float(w & 0xffff0000u); }

#define LDB 136   // 128 + 8 bf16 pad (row stride of the B LDS image)
#define LDC 194   // 192 + 2 bf16 pad for the epilogue transpose

// ---------- GEMM: qkv(bf16, [q|k|v] layout) = x @ W via MFMA ----------
// Block: 256 thr = 4 waves, 64 rows. Full K=128, full N=192 per block.
__global__ __launch_bounds__(256) void gemm_qkv(const float* __restrict__ x,
                                                const float* __restrict__ W,
                                                unsigned short* __restrict__ qkv) {
    __shared__ unsigned short Bt[FTOT * LDB];           // 52224 B
    unsigned short* Ct = Bt;                            // reused after MFMAs
    const int tid = threadIdx.x;

    // stage W -> Bt[n][k] (transposed, bf16): in-block, W is L2-resident
#pragma unroll
    for (int i = 0; i < 12; i++) {
        int idx = tid + i * 256;            // 0..3071
        int n = idx % 192, kg = idx / 192;  // kg 0..15
        int k0 = kg * 8;
        unsigned short tmp[8];
#pragma unroll
        for (int j = 0; j < 8; j++)
            tmp[j] = f2bf(W[(k0 + j) * FTOT + n]);   // lanes sweep n: coalesced
        *(uint4*)(&Bt[n * LDB + k0]) = *(const uint4*)tmp;
    }

    const int wave = tid >> 6, lane = tid & 63;
    const int m = lane & 15, q = lane >> 4;
    const int row = blockIdx.x * 64 + wave * 16 + m;
    const int rowc = min(row, N_NODES - 1);

    // A fragments: lane holds x[row][ s*32 + q*8 .. +7 ]
    short8 a[4];
    const float* xr = x + rowc * FIN;
#pragma unroll
    for (int s = 0; s < 4; s++) {
        float4v f0 = *(const float4v*)(xr + s * 32 + q * 8);
        float4v f1 = *(const float4v*)(xr + s * 32 + q * 8 + 4);
        short8 av;
        av[0] = (short)f2bf(f0.x); av[1] = (short)f2bf(f0.y);
        av[2] = (short)f2bf(f0.z); av[3] = (short)f2bf(f0.w);
        av[4] = (short)f2bf(f1.x); av[5] = (short)f2bf(f1.y);
        av[6] = (short)f2bf(f1.z); av[7] = (short)f2bf(f1.w);
        a[s] = av;
    }
    __syncthreads();

    float4v acc[12];
#pragma unroll
    for (int ct = 0; ct < 12; ct++) acc[ct] = (float4v){0.f, 0.f, 0.f, 0.f};
#pragma unroll
    for (int ct = 0; ct < 12; ct++) {
#pragma unroll
        for (int s = 0; s < 4; s++) {
            short8 b = *(const short8*)(&Bt[(ct * 16 + m) * LDB + s * 32 + q * 8]);
            acc[ct] = __builtin_amdgcn_mfma_f32_16x16x32_bf16(a[s], b, acc[ct], 0, 0, 0);
        }
    }
    __syncthreads();   // all Bt reads done; safe to reuse as Ct

    // transpose into LDS tile; plain [q|k|v] layout, q pre-scaled
    const int lrow0 = wave * 16 + q * 4;
#pragma unroll
    for (int ct = 0; ct < 12; ct++) {
        const int col = ct * 16 + m;
        const float scale = (col < FQK) ? 0.35355339059327373f : 1.f;
#pragma unroll
        for (int i = 0; i < 4; i++)
            Ct[(lrow0 + i) * LDC + col] = f2bf(acc[ct][i] * scale);
    }
    __syncthreads();

    // coalesced store: 64 rows x 96 dwords
    unsigned int* qg = (unsigned int*)qkv;
    const int base = blockIdx.x * 64;
#pragma unroll
    for (int i = 0; i < 24; i++) {
        int l = tid + i * 256;
        int r = l / 96, dw = l - r * 96;
        if (base + r < N_NODES)
            qg[(size_t)(base + r) * 96 + dw] = *(const unsigned int*)(&Ct[r * LDC + 2 * dw]);
    }
}

// ---------- attention: half-wave, two temporal phases (k-gather, then v-gather) ----------
// Each phase's random working set is one 6.4 MB region instead of the 12.8 MB
// interleaved table -> higher per-XCD L2 hit rate on the gather.
__global__ __launch_bounds__(256) void attn(const unsigned short* __restrict__ qkv,
                                            const int* __restrict__ dest,
                                            float* __restrict__ out) {
    const int node = blockIdx.x * 4 + (threadIdx.x >> 6);
    const int lane = threadIdx.x & 63;
    const int half = lane >> 5;
    const int l = lane & 31;           // owns slots 2l, 2l+1
    if (node >= N_NODES) return;       // wave-uniform

    const unsigned int qw = *(const unsigned int*)(qkv + node * FTOT + 2 * l);  // pre-scaled q
    const float q0 = bflo(qw), q1 = bfhi(qw);
    const int dj = dest[node * DEG + (lane & 15)];

    // ---- phase 1: k gather (random over the 6.4 MB k-region) ----
    int doff[8];
    unsigned int kk[8];
#pragma unroll
    for (int t = 0; t < 8; t++) {
        const int d = __shfl(dj, 2 * t + half, 64);
        doff[t] = d * FTOT;
        kk[t] = *(const unsigned int*)(qkv + doff[t] + 64 + 2 * l);
    }

    float lg[8];
#pragma unroll
    for (int t = 0; t < 8; t++) {
        float p = fmaf(q0, bflo(kk[t]), q1 * bfhi(kk[t]));
        p += __shfl_xor(p, 1, 64);     // reduce over the head's 4 lanes
        p += __shfl_xor(p, 2, 64);
        lg[t] = p;
    }
    float mx = lg[0];
#pragma unroll
    for (int t = 1; t < 8; t++) mx = fmaxf(mx, lg[t]);
    mx = fmaxf(mx, __shfl_xor(mx, 32, 64));   // global max -> additive merge later

    // ---- phase 2: v gather (random over the 6.4 MB v-region) ----
    unsigned int vv[8];
#pragma unroll
    for (int t = 0; t < 8; t++)
        vv[t] = *(const unsigned int*)(qkv + doff[t] + 128 + 2 * l);

    float s = 0.f, o0 = 0.f, o1 = 0.f;
#pragma unroll
    for (int t = 0; t < 8; t++) {
        const float p = __expf(lg[t] - mx);
        s += p;
        o0 = fmaf(p, bflo(vv[t]), o0);
        o1 = fmaf(p, bfhi(vv[t]), o1);
    }
    // merge the two halves (global max already shared: plain adds)
    s  += __shfl_xor(s, 32, 64);
    o0 += __shfl_xor(o0, 32, 64);
    o1 += __shfl_xor(o1, 32, 64);
    if (half == 0) {
        float2 r; r.x = o0 / s; r.y = o1 / s;
        *(float2*)(out + node * 64 + 2 * l) = r;
    }
}

extern "C" void kernel_launch(void* const* d_in, const int* in_sizes, int n_in,
                              void* d_out, int out_size, void* d_ws, size_t ws_size,
                              hipStream_t stream) {
    const float* x = (const float*)d_in[0];
    const float* W = (const float*)d_in[1];
    // d_in[2] = batch (unused by reference)
    const int* ei = (const int*)d_in[3];
    const int* dest = ei + E_EDGES;  // ei[1]
    float* out = (float*)d_out;

    unsigned short* qkv = (unsigned short*)d_ws;   // 19.2 MB scratch

    gemm_qkv<<<(N_NODES + 63) / 64, 256, 0, stream>>>(x, W, qkv);
    attn<<<(N_NODES + 3) / 4, 256, 0, stream>>>(qkv, dest, out);
}